// Round 7
// baseline (257.325 us; speedup 1.0000x reference)
//
#include <hip/hip_runtime.h>
#include <stdint.h>

typedef __bf16 bf16x8 __attribute__((ext_vector_type(8)));
typedef float floatx4 __attribute__((ext_vector_type(4)));
typedef unsigned short u16;
typedef u16 u16x8 __attribute__((ext_vector_type(8)));

__device__ __forceinline__ float bf2f(u16 u) {
    union { uint32_t i; float f; } v; v.i = ((uint32_t)u) << 16; return v.f;
}
__device__ __forceinline__ u16 f2bf(float f) {
    union { float f; uint32_t i; } v; v.f = f;
    uint32_t r = v.i + 0x7fffu + ((v.i >> 16) & 1u);
    return (u16)(r >> 16);
}

// async global->LDS, 16B per lane. LDS dest wave-uniform base; HW adds lane*16.
__device__ __forceinline__ void gload_lds16(const u16* g, u16* l) {
    __builtin_amdgcn_global_load_lds(
        (const __attribute__((address_space(1))) void*)g,
        (__attribute__((address_space(3))) void*)l,
        16, 0, 0);
}

#define BK 64
// 256x256 tile, 8 waves (2M x 4N), m201-style sub-phased pipeline:
// per K-tile 4 phases, each {ds_read subtile [+stage burst at P0] -> barrier ->
// lgkmcnt(0) -> setprio(1) 16 MFMA setprio(0) -> barrier}. One vmcnt gate per
// K-tile (at P3, for tile t+1's loads issued at P0 — 3.5 phases of lead).
// LDS: 2 buf x [A0|A1|B0|B1] half-tile slots x 16 KB = 128 KiB. 1 block/CU.
// Every wave issues exactly 2 gloads per half-tile (8/K-tile) -> uniform vmcnt.
// Both-sides XOR swizzle (rule 21) retained: measured 0 bank conflicts (R6).
// EPI=0: bf16 out + per-row output ssq -> ssq_out[(col0>>9)*Mtot + row]     (GEMM1)
// EPI=1: bf16 out, acc *= rsqrt(ssq_row[row]), += rsqrt(ssq_add[row])*addsrc (GEMM2)
// EPI=2: fp32 out, plain bias                                                (GEMM3)
template<int EPI>
__global__ __launch_bounds__(512, 2) void gemm_bt(
    const u16* __restrict__ A, int lda,
    const u16* __restrict__ Bt, long bstride,
    const float* __restrict__ bias,
    const u16* __restrict__ addsrc, int ldadd,
    const float* __restrict__ ssq_add,
    const float* __restrict__ ssq_row,
    float* __restrict__ ssq_out,
    u16* __restrict__ C16, float* __restrict__ C32, int ldc,
    int K)
{
    __shared__ __attribute__((aligned(16))) u16 lds[2 * 32768];  // 128 KiB
    const int tid  = threadIdx.x;
    const int wave = tid >> 6;
    const int lane = tid & 63;
    const int quad = lane >> 4;
    const int l16  = lane & 15;
    const int wm = wave >> 2, wn = wave & 3;   // 2 x 4 wave grid; per-wave out 128x64

    // XCD-aware chunked swizzle (all launches have nwg % 8 == 0)
    const int gx   = gridDim.x;
    const int nwg  = gx * gridDim.y;
    const int wgid = blockIdx.y * gx + blockIdx.x;
    const int cpx  = nwg >> 3;
    const int swz  = (wgid & 7) * cpx + (wgid >> 3);
    const int row0 = (swz / gx) * 256;
    const int col0 = (swz % gx) * 256;
    const int batch = row0 >> 12;
    const int Mtot  = gridDim.y * 256;

    floatx4 acc[8][4] = {};

    // staging bases: half-tile h, load j: row_in_half = j*64 + wave*8 + rsub,
    // k-offset pre-swizzled by row&7 (= rsub) so linear LDS dest + swizzled ds_read agree.
    const int rsub = lane >> 3;
    const int ksub = ((lane & 7) ^ rsub) << 3;
    const u16* Bb = Bt + (size_t)batch * bstride;
    const u16* aP = A  + (size_t)(row0 + wave * 8 + rsub) * lda + ksub;
    const u16* bP = Bb + (size_t)(col0 + wave * 8 + rsub) * K   + ksub;

    const int NT = K >> 6;   // 8 for all our calls (>= 2 required)

#define STAGE(T)                                                              \
    {                                                                         \
        u16* dst_ = &lds[((T) & 1) * 32768];                                  \
        const int kt_ = (T) * BK;                                             \
        _Pragma("unroll")                                                     \
        for (int h_ = 0; h_ < 2; ++h_)                                        \
        { _Pragma("unroll")                                                   \
          for (int j_ = 0; j_ < 2; ++j_) {                                    \
            gload_lds16(aP + (size_t)(h_ * 128 + j_ * 64) * lda + kt_,        \
                        dst_ + h_ * 8192 + j_ * 4096 + wave * 512);           \
            gload_lds16(bP + (size_t)(h_ * 128 + j_ * 64) * K + kt_,          \
                        dst_ + 16384 + h_ * 8192 + j_ * 4096 + wave * 512);   \
          } }                                                                 \
    }

    // prologue: tile 0 staged and landed before first ds_read
    STAGE(0);
    asm volatile("s_waitcnt vmcnt(0)" ::: "memory");
    __builtin_amdgcn_s_barrier();

    for (int t = 0; t < NT; ++t) {
        const u16* buf = &lds[(t & 1) * 32768];
        const u16* sA = buf + wm * 8192;                 // wave's A half-tile slot
        const u16* sB = buf + 16384 + (wn >> 1) * 8192;  // wave's B half-tile slot
        const int brl = (wn & 1) * 64;                   // B row-local base
        bf16x8 af[4][2], bb[2][2];

        // ---- P0: ds_read af(m0-3) + bb(n0-1) [12]; stage tile t+1 burst; MFMA m0-3 x n0-1
#pragma unroll
        for (int m = 0; m < 4; ++m)
#pragma unroll
            for (int ks = 0; ks < 2; ++ks)
                af[m][ks] = *(const bf16x8*)&sA[(m * 16 + l16) * 64 + (((ks * 4 + quad) ^ (l16 & 7)) << 3)];
#pragma unroll
        for (int n = 0; n < 2; ++n)
#pragma unroll
            for (int ks = 0; ks < 2; ++ks)
                bb[n][ks] = *(const bf16x8*)&sB[(brl + n * 16 + l16) * 64 + (((ks * 4 + quad) ^ (l16 & 7)) << 3)];
        if (t + 1 < NT) STAGE(t + 1);
        __builtin_amdgcn_sched_barrier(0);
        __builtin_amdgcn_s_barrier();
        asm volatile("s_waitcnt lgkmcnt(0)" ::: "memory");
        __builtin_amdgcn_sched_barrier(0);
        __builtin_amdgcn_s_setprio(1);
#pragma unroll
        for (int ks = 0; ks < 2; ++ks)
#pragma unroll
            for (int m = 0; m < 4; ++m)
#pragma unroll
                for (int n = 0; n < 2; ++n)
                    acc[m][n] = __builtin_amdgcn_mfma_f32_16x16x32_bf16(af[m][ks], bb[n][ks], acc[m][n], 0, 0, 0);
        __builtin_amdgcn_s_setprio(0);
        __builtin_amdgcn_sched_barrier(0);
        __builtin_amdgcn_s_barrier();

        // ---- P1: ds_read bb(n2-3) [4]; MFMA m0-3 x n2-3 (af kept in regs)
#pragma unroll
        for (int n = 0; n < 2; ++n)
#pragma unroll
            for (int ks = 0; ks < 2; ++ks)
                bb[n][ks] = *(const bf16x8*)&sB[(brl + (n + 2) * 16 + l16) * 64 + (((ks * 4 + quad) ^ (l16 & 7)) << 3)];
        __builtin_amdgcn_sched_barrier(0);
        __builtin_amdgcn_s_barrier();
        asm volatile("s_waitcnt lgkmcnt(0)" ::: "memory");
        __builtin_amdgcn_sched_barrier(0);
        __builtin_amdgcn_s_setprio(1);
#pragma unroll
        for (int ks = 0; ks < 2; ++ks)
#pragma unroll
            for (int m = 0; m < 4; ++m)
#pragma unroll
                for (int n = 0; n < 2; ++n)
                    acc[m][n + 2] = __builtin_amdgcn_mfma_f32_16x16x32_bf16(af[m][ks], bb[n][ks], acc[m][n + 2], 0, 0, 0);
        __builtin_amdgcn_s_setprio(0);
        __builtin_amdgcn_sched_barrier(0);
        __builtin_amdgcn_s_barrier();

        // ---- P2: ds_read af(m4-7) + bb(n0-1) [12]; MFMA m4-7 x n0-1
#pragma unroll
        for (int m = 0; m < 4; ++m)
#pragma unroll
            for (int ks = 0; ks < 2; ++ks)
                af[m][ks] = *(const bf16x8*)&sA[((m + 4) * 16 + l16) * 64 + (((ks * 4 + quad) ^ (l16 & 7)) << 3)];
#pragma unroll
        for (int n = 0; n < 2; ++n)
#pragma unroll
            for (int ks = 0; ks < 2; ++ks)
                bb[n][ks] = *(const bf16x8*)&sB[(brl + n * 16 + l16) * 64 + (((ks * 4 + quad) ^ (l16 & 7)) << 3)];
        __builtin_amdgcn_sched_barrier(0);
        __builtin_amdgcn_s_barrier();
        asm volatile("s_waitcnt lgkmcnt(0)" ::: "memory");
        __builtin_amdgcn_sched_barrier(0);
        __builtin_amdgcn_s_setprio(1);
#pragma unroll
        for (int ks = 0; ks < 2; ++ks)
#pragma unroll
            for (int m = 0; m < 4; ++m)
#pragma unroll
                for (int n = 0; n < 2; ++n)
                    acc[m + 4][n] = __builtin_amdgcn_mfma_f32_16x16x32_bf16(af[m][ks], bb[n][ks], acc[m + 4][n], 0, 0, 0);
        __builtin_amdgcn_s_setprio(0);
        __builtin_amdgcn_sched_barrier(0);
        __builtin_amdgcn_s_barrier();

        // ---- P3: ds_read bb(n2-3) [4]; MFMA m4-7 x n2-3; gate tile t+1 loads; barrier
#pragma unroll
        for (int n = 0; n < 2; ++n)
#pragma unroll
            for (int ks = 0; ks < 2; ++ks)
                bb[n][ks] = *(const bf16x8*)&sB[(brl + (n + 2) * 16 + l16) * 64 + (((ks * 4 + quad) ^ (l16 & 7)) << 3)];
        __builtin_amdgcn_sched_barrier(0);
        __builtin_amdgcn_s_barrier();
        asm volatile("s_waitcnt lgkmcnt(0)" ::: "memory");
        __builtin_amdgcn_sched_barrier(0);
        __builtin_amdgcn_s_setprio(1);
#pragma unroll
        for (int ks = 0; ks < 2; ++ks)
#pragma unroll
            for (int m = 0; m < 4; ++m)
#pragma unroll
                for (int n = 0; n < 2; ++n)
                    acc[m + 4][n + 2] = __builtin_amdgcn_mfma_f32_16x16x32_bf16(af[m][ks], bb[n][ks], acc[m + 4][n + 2], 0, 0, 0);
        __builtin_amdgcn_s_setprio(0);
        __builtin_amdgcn_sched_barrier(0);
        if (t + 1 < NT) asm volatile("s_waitcnt vmcnt(0)" ::: "memory");  // t+1 loads (issued P0, ~3.5 phases ago)
        __builtin_amdgcn_s_barrier();
    }
#undef STAGE

    // ---------------- epilogue (validated R6). C/D layout: col=lane&15, row=quad*4+reg ----
    if constexpr (EPI == 0 || EPI == 1) {
        u16* til = lds;  // [128][264] u16 = 67584 B, aliases staging LDS (loop drained)
#pragma unroll
        for (int h = 0; h < 2; ++h) {
            __syncthreads();
            if (wm == h) {
                float bv[4];
#pragma unroll
                for (int n = 0; n < 4; ++n) bv[n] = bias[col0 + wn * 64 + n * 16 + l16];
#pragma unroll
                for (int m = 0; m < 8; ++m) {
                    int rowl = m * 16 + quad * 4;
                    int rowb = row0 + h * 128 + rowl;
                    float rsr4[4], rsa4[4];
                    if constexpr (EPI == 1) {
                        float4 rr = *(const float4*)&ssq_row[rowb];
                        float4 ra = *(const float4*)&ssq_add[rowb];
                        rsr4[0] = rsqrtf(fmaxf(rr.x, 1e-12f));
                        rsr4[1] = rsqrtf(fmaxf(rr.y, 1e-12f));
                        rsr4[2] = rsqrtf(fmaxf(rr.z, 1e-12f));
                        rsr4[3] = rsqrtf(fmaxf(rr.w, 1e-12f));
                        rsa4[0] = rsqrtf(fmaxf(ra.x, 1e-12f));
                        rsa4[1] = rsqrtf(fmaxf(ra.y, 1e-12f));
                        rsa4[2] = rsqrtf(fmaxf(ra.z, 1e-12f));
                        rsa4[3] = rsqrtf(fmaxf(ra.w, 1e-12f));
                    }
#pragma unroll
                    for (int n = 0; n < 4; ++n) {
                        int tcol = wn * 64 + n * 16 + l16;
#pragma unroll
                        for (int t = 0; t < 4; ++t) {
                            float v;
                            if constexpr (EPI == 1) {
                                v = acc[m][n][t] * rsr4[t] + bv[n]
                                  + bf2f(addsrc[(size_t)(rowb + t) * ldadd + col0 + tcol]) * rsa4[t];
                            } else {
                                v = acc[m][n][t] + bv[n];
                            }
                            til[(rowl + t) * 264 + tcol] = f2bf(v);
                        }
                    }
                }
            }
            __syncthreads();
            float ssl[8];
#pragma unroll
            for (int c = 0; c < 8; ++c) {
                int r  = c * 16 + (tid >> 5);
                int cu = (tid & 31) * 8;
                ushort4 lo = *(const ushort4*)&til[r * 264 + cu];
                ushort4 hi = *(const ushort4*)&til[r * 264 + cu + 4];
                u16x8 o;
                o[0] = lo.x; o[1] = lo.y; o[2] = lo.z; o[3] = lo.w;
                o[4] = hi.x; o[5] = hi.y; o[6] = hi.z; o[7] = hi.w;
                *(u16x8*)&C16[(size_t)(row0 + h * 128 + r) * ldc + col0 + cu] = o;
                if constexpr (EPI == 0) {
                    float ss = 0.f;
#pragma unroll
                    for (int q2 = 0; q2 < 8; ++q2) { float f = bf2f(o[q2]); ss += f * f; }
                    ssl[c] = ss;
                }
            }
            if constexpr (EPI == 0) {
                float* so = ssq_out + (size_t)(col0 >> 9) * Mtot + row0 + h * 128;
#pragma unroll
                for (int c = 0; c < 8; ++c) {
                    float s = ssl[c];
                    s += __shfl_xor(s, 1);
                    s += __shfl_xor(s, 2);
                    s += __shfl_xor(s, 4);
                    s += __shfl_xor(s, 8);
                    s += __shfl_xor(s, 16);
                    if ((lane & 31) == 0) atomicAdd(&so[c * 16 + (tid >> 5)], s);
                }
            }
        }
    } else {
        // EPI=2: fp32 out, 4 passes of 64 rows through a [64][264] f32 tile
        float* ftile = (float*)lds;
#pragma unroll
        for (int p = 0; p < 4; ++p) {
            __syncthreads();
            if (wm == (p >> 1)) {
                float bv[4];
#pragma unroll
                for (int n = 0; n < 4; ++n) bv[n] = bias[col0 + wn * 64 + n * 16 + l16];
#pragma unroll
                for (int mi = 0; mi < 4; ++mi) {
                    int m = (p & 1) * 4 + mi;
                    int rowl = mi * 16 + quad * 4;
#pragma unroll
                    for (int n = 0; n < 4; ++n) {
                        int tcol = wn * 64 + n * 16 + l16;
#pragma unroll
                        for (int t = 0; t < 4; ++t)
                            ftile[(rowl + t) * 264 + tcol] = acc[m][n][t] + bv[n];
                    }
                }
            }
            __syncthreads();
#pragma unroll
            for (int c = 0; c < 8; ++c) {
                int r  = c * 8 + wave;
                int cu = lane * 4;
                float4 v = *(const float4*)&ftile[r * 264 + cu];
                *(float4*)&C32[(size_t)(row0 + p * 64 + r) * ldc + col0 + cu] = v;
            }
        }
    }
}

// g[b,:] += sum_rows rsqrt(ssqQ[row]) * Q[row,:]   (Q = cols 0..511 of QK, raw bf16)
__global__ __launch_bounds__(256) void gsum_kernel(const u16* __restrict__ QK,
                                                   const float* __restrict__ ssqQ,
                                                   float* __restrict__ g)
{
    __shared__ float gtile[4][512];
    const int lane = threadIdx.x & 63;
    const int wave = threadIdx.x >> 6;
    const int row0 = blockIdx.x * 128 + wave * 32;
    const int batch = row0 >> 12;
    const int d = lane * 8;
    float gacc[8] = {};
    for (int rr = 0; rr < 32; ++rr) {
        int row = row0 + rr;
        float s = rsqrtf(fmaxf(ssqQ[row], 1e-12f));
        u16x8 q = *(const u16x8*)(QK + (size_t)row * 1024 + d);
#pragma unroll
        for (int i = 0; i < 8; ++i) gacc[i] += s * bf2f(q[i]);
    }
#pragma unroll
    for (int i = 0; i < 8; ++i) gtile[wave][d + i] = gacc[i];
    __syncthreads();
    int c2 = threadIdx.x * 2;
    float s0 = gtile[0][c2]     + gtile[1][c2]     + gtile[2][c2]     + gtile[3][c2];
    float s1 = gtile[0][c2 + 1] + gtile[1][c2 + 1] + gtile[2][c2 + 1] + gtile[3][c2 + 1];
    atomicAdd(&g[batch * 512 + c2], s0);
    atomicAdd(&g[batch * 512 + c2 + 1], s1);
}

// BtP8[b][n][k] = bf16(g[b][k] * wp[k][n])  — folds the g scaling into per-batch weights.
__global__ __launch_bounds__(256) void scale_wp_kernel(const float* __restrict__ wp,
                                                       const float* __restrict__ g,
                                                       u16* __restrict__ BtP8)
{
    __shared__ u16 tile[32][34];
    const int b   = blockIdx.x >> 8;
    const int bid = blockIdx.x & 255;
    const int tk = bid & 15;
    const int tn = bid >> 4;
    const int c  = threadIdx.x & 31;
    const int r0 = threadIdx.x >> 5;
    const float* gb = g + b * 512;
#pragma unroll
    for (int i = 0; i < 4; ++i) {
        int r = r0 + i * 8;
        int k = tk * 32 + r;
        tile[r][c] = f2bf(gb[k] * wp[(size_t)k * 512 + tn * 32 + c]);
    }
    __syncthreads();
    u16* Bt = BtP8 + (size_t)b * 512 * 512;
#pragma unroll
    for (int i = 0; i < 4; ++i) {
        int r = r0 + i * 8;
        Bt[(size_t)(tn * 32 + r) * 512 + tk * 32 + c] = tile[c][r];
    }
}

// x (fp32) -> bf16
__global__ __launch_bounds__(256) void convert_x_kernel(const float* __restrict__ x, u16* __restrict__ xb)
{
    size_t i = ((size_t)blockIdx.x * 256 + threadIdx.x) * 4;
    float4 v = *(const float4*)(x + i);
    ushort4 o;
    o.x = f2bf(v.x); o.y = f2bf(v.y); o.z = f2bf(v.z); o.w = f2bf(v.w);
    *(ushort4*)(xb + i) = o;
}

// LDS-tiled transpose of three 512x512 fp32 weights (wq, wk, wf) -> bf16 B^T layout.
__global__ __launch_bounds__(256) void transpose3_kernel(
    const float* __restrict__ w0, const float* __restrict__ w1, const float* __restrict__ w2,
    u16* __restrict__ d0, u16* __restrict__ d1, u16* __restrict__ d2)
{
    __shared__ u16 tile[32][34];
    const int which = blockIdx.x >> 8;
    const float* W = (which == 0) ? w0 : (which == 1) ? w1 : w2;
    u16* Bt = (which == 0) ? d0 : (which == 1) ? d1 : d2;
    const int bid = blockIdx.x & 255;
    const int tk = bid & 15;
    const int tn = bid >> 4;
    const int c  = threadIdx.x & 31;
    const int r0 = threadIdx.x >> 5;
#pragma unroll
    for (int i = 0; i < 4; ++i) {
        int r = r0 + i * 8;
        tile[r][c] = f2bf(W[(size_t)(tk * 32 + r) * 512 + tn * 32 + c]);
    }
    __syncthreads();
#pragma unroll
    for (int i = 0; i < 4; ++i) {
        int r = r0 + i * 8;
        Bt[(size_t)(tn * 32 + r) * 512 + tk * 32 + c] = tile[c][r];
    }
}

// setup: biasQK = [bq|bk]; g = 0; ssq = 0
__global__ __launch_bounds__(256) void setup_kernel(const float* __restrict__ bq,
                                                    const float* __restrict__ bk,
                                                    float* __restrict__ biasQK,
                                                    float* __restrict__ g,
                                                    float* __restrict__ ssq)
{
    int id = blockIdx.x * 256 + threadIdx.x;   // 0..65535
    if (id < 1024) biasQK[id] = (id < 512) ? bq[id] : bk[id - 512];
    if (id < 4096) g[id] = 0.f;
    ssq[id] = 0.f;                             // 2 x 32768
}

extern "C" void kernel_launch(void* const* d_in, const int* in_sizes, int n_in,
                              void* d_out, int out_size, void* d_ws, size_t ws_size,
                              hipStream_t stream)
{
    const float* x  = (const float*)d_in[0];
    const float* wq = (const float*)d_in[1];
    const float* bq = (const float*)d_in[2];
    const float* wk = (const float*)d_in[3];
    const float* bk = (const float*)d_in[4];
    const float* wp = (const float*)d_in[5];
    const float* bp = (const float*)d_in[6];
    const float* wf = (const float*)d_in[7];
    const float* bf = (const float*)d_in[8];
    // d_in[9] = w_g unused: softmax over a size-1 axis is identically 1.

    char* ws = (char*)d_ws;
    u16*   xb     = (u16*)(ws);                 // 32768 x 512 bf16 = 32 MiB
    u16*   T      = (u16*)(ws);                 // alias: xb dead after GEMM1
    u16*   QK     = (u16*)(ws + 33554432);      // 32768 x 1024 bf16 = 64 MiB
    u16*   Bt1    = (u16*)(ws + 100663296);     // 1024 x 512 bf16 = 1 MiB
    u16*   BtP8   = (u16*)(ws + 101711872);     // 8 x 512 x 512 bf16 = 4 MiB
    u16*   BtF    = (u16*)(ws + 105906176);     // 512 x 512 bf16
    float* biasQK = (float*)(ws + 106430464);   // 1024 fp32
    float* g      = (float*)(ws + 106434560);   // 8 x 512 fp32
    float* ssq    = (float*)(ws + 106450944);   // 2 x 32768 fp32 (Q norms, K norms)

    setup_kernel<<<256, 256, 0, stream>>>(bq, bk, biasQK, g, ssq);
    convert_x_kernel<<<16384, 256, 0, stream>>>(x, xb);
    transpose3_kernel<<<768, 256, 0, stream>>>(wq, wk, wf, Bt1, Bt1 + 512 * 512, BtF);

    // QK = x @ [wq|wk] + [bq|bk]  (bf16 out) + per-row ssq of Q,K halves   nwg = 512
    gemm_bt<0><<<dim3(4, 128), 512, 0, stream>>>(
        xb, 512, Bt1, 0, biasQK, nullptr, 0, nullptr, nullptr, ssq, QK, nullptr, 1024, 512);
    // g[b,:] = sum_rows rsqrt(ssqQ[r]) * Q[r,:]
    gsum_kernel<<<256, 256, 0, stream>>>(QK, ssq, g);
    // fold g into per-batch wp:  BtP8[b] = (diag(g[b]) @ wp)^T
    scale_wp_kernel<<<2048, 256, 0, stream>>>(wp, g, BtP8);
    // T = rsk[row]*(Kraw @ (g*wp)) + bp + rsq[row]*Qraw   (bf16 out)       nwg = 256
    gemm_bt<1><<<dim3(2, 128), 512, 0, stream>>>(
        QK + 512, 1024, BtP8, 512 * 512, bp, QK, 1024, ssq, ssq + 32768, nullptr, T, nullptr, 512, 512);
    // out = T @ wf + bf   (fp32 out)                                       nwg = 256
    gemm_bt<2><<<dim3(2, 128), 512, 0, stream>>>(
        T, 512, BtF, 0, bf, nullptr, 0, nullptr, nullptr, nullptr, nullptr, (float*)d_out, 512, 512);
}

// Round 8
// 256.029 us; speedup vs baseline: 1.0051x; 1.0051x over previous
//
#include <hip/hip_runtime.h>
#include <stdint.h>

typedef __bf16 bf16x8 __attribute__((ext_vector_type(8)));
typedef float floatx4 __attribute__((ext_vector_type(4)));
typedef unsigned short u16;
typedef u16 u16x8 __attribute__((ext_vector_type(8)));

__device__ __forceinline__ float bf2f(u16 u) {
    union { uint32_t i; float f; } v; v.i = ((uint32_t)u) << 16; return v.f;
}
__device__ __forceinline__ u16 f2bf(float f) {
    union { float f; uint32_t i; } v; v.f = f;
    uint32_t r = v.i + 0x7fffu + ((v.i >> 16) & 1u);
    return (u16)(r >> 16);
}

// async global->LDS, 16B per lane. LDS dest wave-uniform base; HW adds lane*16.
__device__ __forceinline__ void gload_lds16(const u16* g, u16* l) {
    __builtin_amdgcn_global_load_lds(
        (const __attribute__((address_space(1))) void*)g,
        (__attribute__((address_space(3))) void*)l,
        16, 0, 0);
}

#define BK 64

// ============ GEMM1: QK = xb @ [wq|wk]^T + biasQK, bf16 out + per-row ssq =============
// 256x256 tile, 8 waves, R6 depth-2 counted-vmcnt body (proven). lda=512, ldc=1024, K=512.
__global__ __launch_bounds__(512, 2) void gemm1_kernel(
    const u16* __restrict__ A,        // xb [32768][512]
    const u16* __restrict__ Bt,       // Bt1 [1024][512]
    const float* __restrict__ bias,   // biasQK [1024]
    float* __restrict__ ssq_out,      // [2][32768]
    u16* __restrict__ C16)            // QK [32768][1024]
{
    __shared__ __attribute__((aligned(16))) u16 lds[2 * 32768];  // 128 KiB
    const int tid  = threadIdx.x;
    const int wave = tid >> 6;
    const int lane = tid & 63;
    const int quad = lane >> 4;
    const int l16  = lane & 15;
    const int wm = wave >> 2, wn = wave & 3;

    const int gx   = gridDim.x;                 // 4
    const int nwg  = gx * gridDim.y;            // 512, %8==0
    const int wgid = blockIdx.y * gx + blockIdx.x;
    const int cpx  = nwg >> 3;
    const int swz  = (wgid & 7) * cpx + (wgid >> 3);
    const int row0 = (swz / gx) * 256;
    const int col0 = (swz % gx) * 256;

    floatx4 acc[8][4] = {};

    const int rsub = lane >> 3;
    const int ksub = ((lane & 7) ^ rsub) << 3;  // XOR pre-swizzle (rule 21)
    const u16* aptr[4]; const u16* bptr[4];
#pragma unroll
    for (int c = 0; c < 4; ++c) {
        const int cc = wave * 4 + c;
        aptr[c] = A  + (size_t)(row0 + cc * 8 + rsub) * 512 + ksub;
        bptr[c] = Bt + (size_t)(col0 + cc * 8 + rsub) * 512 + ksub;
    }
    const int NT = 8;

#define STAGE1(T, B)                                                          \
    {                                                                         \
        u16* dA_ = &lds[(B) * 32768];                                         \
        u16* dB_ = dA_ + 16384;                                               \
        const int kt_ = (T) * BK;                                             \
        _Pragma("unroll")                                                     \
        for (int c = 0; c < 4; ++c) {                                         \
            const int cc = wave * 4 + c;                                      \
            gload_lds16(aptr[c] + kt_, dA_ + cc * 512);                       \
            gload_lds16(bptr[c] + kt_, dB_ + cc * 512);                       \
        }                                                                     \
    }

    STAGE1(0, 0);
    STAGE1(1, 1);
    for (int t = 0; t < NT; ++t) {
        if (t + 1 < NT) asm volatile("s_waitcnt vmcnt(8)" ::: "memory");
        else            asm volatile("s_waitcnt vmcnt(0)" ::: "memory");
        __builtin_amdgcn_s_barrier();
        __builtin_amdgcn_sched_barrier(0);
        const u16* sA = &lds[(t & 1) * 32768];
        const u16* sB = sA + 16384;
#pragma unroll
        for (int ks = 0; ks < 2; ++ks) {
            const int pgo = (((ks * 4 + quad) ^ (l16 & 7)) << 3);
            bf16x8 bfr[4];
#pragma unroll
            for (int n = 0; n < 4; ++n)
                bfr[n] = *(const bf16x8*)&sB[(wn * 64 + n * 16 + l16) * 64 + pgo];
            __builtin_amdgcn_s_setprio(1);
#pragma unroll
            for (int m = 0; m < 8; ++m) {
                bf16x8 af = *(const bf16x8*)&sA[(wm * 128 + m * 16 + l16) * 64 + pgo];
#pragma unroll
                for (int n = 0; n < 4; ++n)
                    acc[m][n] = __builtin_amdgcn_mfma_f32_16x16x32_bf16(af, bfr[n], acc[m][n], 0, 0, 0);
            }
            __builtin_amdgcn_s_setprio(0);
        }
        __builtin_amdgcn_sched_barrier(0);
        asm volatile("" ::: "memory");
        __builtin_amdgcn_s_barrier();
        asm volatile("" ::: "memory");
        if (t + 2 < NT) STAGE1(t + 2, t & 1);
    }
#undef STAGE1

    // epilogue: bf16 repack + per-row output ssq (validated R5-R7)
    u16* til = lds;  // [128][264]
#pragma unroll
    for (int h = 0; h < 2; ++h) {
        __syncthreads();
        if (wm == h) {
            float bv[4];
#pragma unroll
            for (int n = 0; n < 4; ++n) bv[n] = bias[col0 + wn * 64 + n * 16 + l16];
#pragma unroll
            for (int m = 0; m < 8; ++m) {
                int rowl = m * 16 + quad * 4;
#pragma unroll
                for (int n = 0; n < 4; ++n) {
                    int tcol = wn * 64 + n * 16 + l16;
#pragma unroll
                    for (int t = 0; t < 4; ++t)
                        til[(rowl + t) * 264 + tcol] = f2bf(acc[m][n][t] + bv[n]);
                }
            }
        }
        __syncthreads();
        float ssl[8];
#pragma unroll
        for (int c = 0; c < 8; ++c) {
            int r  = c * 16 + (tid >> 5);
            int cu = (tid & 31) * 8;
            ushort4 lo = *(const ushort4*)&til[r * 264 + cu];
            ushort4 hi = *(const ushort4*)&til[r * 264 + cu + 4];
            u16x8 o;
            o[0] = lo.x; o[1] = lo.y; o[2] = lo.z; o[3] = lo.w;
            o[4] = hi.x; o[5] = hi.y; o[6] = hi.z; o[7] = hi.w;
            *(u16x8*)&C16[(size_t)(row0 + h * 128 + r) * 1024 + col0 + cu] = o;
            float ss = 0.f;
#pragma unroll
            for (int q2 = 0; q2 < 8; ++q2) { float f = bf2f(o[q2]); ss += f * f; }
            ssl[c] = ss;
        }
        float* so = ssq_out + (size_t)(col0 >> 9) * 32768 + row0 + h * 128;
#pragma unroll
        for (int c = 0; c < 8; ++c) {
            float s = ssl[c];
            s += __shfl_xor(s, 1);
            s += __shfl_xor(s, 2);
            s += __shfl_xor(s, 4);
            s += __shfl_xor(s, 8);
            s += __shfl_xor(s, 16);
            if ((lane & 31) == 0) atomicAdd(&so[c * 16 + (tid >> 5)], s);
        }
    }
}

// ====== fused GEMM23: out = rsq*(Q@wf) + rsk*(K@diag(g)(wp@wf)) + bpf, fp32 out =======
// A = raw QK (lda 1024), K=1024: tiles 0-7 read BtF (wf^T), tiles 8-15 read BtPF[b].
// Mid-loop (after tile 7): acc *= rsq/rsk. Epilogue: out = acc*rsk + bpf.
__global__ __launch_bounds__(512, 2) void gemm_qk_kernel(
    const u16* __restrict__ A,        // QK [32768][1024]
    const u16* __restrict__ BtF,      // [512][512] wf^T
    const u16* __restrict__ BtPF,     // [8][512][512] diag(g_b)*(wp@wf), n-major
    const float* __restrict__ bpf,    // [512] = bp@wf + bf
    const float* __restrict__ ssqQ,
    const float* __restrict__ ssqK,
    float* __restrict__ C32)          // out [32768][512]
{
    __shared__ __attribute__((aligned(16))) u16 lds[2 * 32768];  // 128 KiB
    const int tid  = threadIdx.x;
    const int wave = tid >> 6;
    const int lane = tid & 63;
    const int quad = lane >> 4;
    const int l16  = lane & 15;
    const int wm = wave >> 2, wn = wave & 3;

    const int gx   = gridDim.x;                 // 2
    const int nwg  = gx * gridDim.y;            // 256, %8==0
    const int wgid = blockIdx.y * gx + blockIdx.x;
    const int cpx  = nwg >> 3;
    const int swz  = (wgid & 7) * cpx + (wgid >> 3);
    const int row0 = (swz / gx) * 256;
    const int col0 = (swz % gx) * 256;
    const int batch = row0 >> 12;

    floatx4 acc[8][4] = {};

    const int rsub = lane >> 3;
    const int ksub = ((lane & 7) ^ rsub) << 3;
    const u16* aptr[4]; const u16* bptrF[4]; const u16* bptrP[4];
    const u16* BP = BtPF + (size_t)batch * 262144;
#pragma unroll
    for (int c = 0; c < 4; ++c) {
        const int cc = wave * 4 + c;
        aptr[c]  = A   + (size_t)(row0 + cc * 8 + rsub) * 1024 + ksub;
        bptrF[c] = BtF + (size_t)(col0 + cc * 8 + rsub) * 512  + ksub;
        bptrP[c] = BP  + (size_t)(col0 + cc * 8 + rsub) * 512  + ksub;
    }
    const int NT = 16;

#define STAGEQ(T, B)                                                          \
    {                                                                         \
        u16* dA_ = &lds[(B) * 32768];                                         \
        u16* dB_ = dA_ + 16384;                                               \
        const int kt_ = (T) * BK;                                             \
        _Pragma("unroll")                                                     \
        for (int c = 0; c < 4; ++c) {                                         \
            const int cc = wave * 4 + c;                                      \
            gload_lds16(aptr[c] + kt_, dA_ + cc * 512);                       \
            const u16* bsrc_ = (kt_ < 512) ? (bptrF[c] + kt_)                 \
                                           : (bptrP[c] + (kt_ - 512));        \
            gload_lds16(bsrc_, dB_ + cc * 512);                               \
        }                                                                     \
    }

    STAGEQ(0, 0);
    STAGEQ(1, 1);
    for (int t = 0; t < NT; ++t) {
        if (t + 1 < NT) asm volatile("s_waitcnt vmcnt(8)" ::: "memory");
        else            asm volatile("s_waitcnt vmcnt(0)" ::: "memory");
        __builtin_amdgcn_s_barrier();
        __builtin_amdgcn_sched_barrier(0);
        const u16* sA = &lds[(t & 1) * 32768];
        const u16* sB = sA + 16384;
#pragma unroll
        for (int ks = 0; ks < 2; ++ks) {
            const int pgo = (((ks * 4 + quad) ^ (l16 & 7)) << 3);
            bf16x8 bfr[4];
#pragma unroll
            for (int n = 0; n < 4; ++n)
                bfr[n] = *(const bf16x8*)&sB[(wn * 64 + n * 16 + l16) * 64 + pgo];
            __builtin_amdgcn_s_setprio(1);
#pragma unroll
            for (int m = 0; m < 8; ++m) {
                bf16x8 af = *(const bf16x8*)&sA[(wm * 128 + m * 16 + l16) * 64 + pgo];
#pragma unroll
                for (int n = 0; n < 4; ++n)
                    acc[m][n] = __builtin_amdgcn_mfma_f32_16x16x32_bf16(af, bfr[n], acc[m][n], 0, 0, 0);
            }
            __builtin_amdgcn_s_setprio(0);
        }
        // end of Q-half: acc holds Sq = Q@wf; rescale so final *rsk yields rsq*Sq + rsk*Sk
        if (t == 7) {
#pragma unroll
            for (int m = 0; m < 8; ++m) {
                int rowb = row0 + wm * 128 + m * 16 + quad * 4;
                float4 q4 = *(const float4*)&ssqQ[rowb];
                float4 k4 = *(const float4*)&ssqK[rowb];
                float ratio[4];
                ratio[0] = rsqrtf(fmaxf(q4.x, 1e-12f)) / rsqrtf(fmaxf(k4.x, 1e-12f));
                ratio[1] = rsqrtf(fmaxf(q4.y, 1e-12f)) / rsqrtf(fmaxf(k4.y, 1e-12f));
                ratio[2] = rsqrtf(fmaxf(q4.z, 1e-12f)) / rsqrtf(fmaxf(k4.z, 1e-12f));
                ratio[3] = rsqrtf(fmaxf(q4.w, 1e-12f)) / rsqrtf(fmaxf(k4.w, 1e-12f));
#pragma unroll
                for (int n = 0; n < 4; ++n)
#pragma unroll
                    for (int tt = 0; tt < 4; ++tt)
                        acc[m][n][tt] *= ratio[tt];
            }
        }
        __builtin_amdgcn_sched_barrier(0);
        asm volatile("" ::: "memory");
        __builtin_amdgcn_s_barrier();
        asm volatile("" ::: "memory");
        if (t + 2 < NT) STAGEQ(t + 2, t & 1);
    }
#undef STAGEQ

    // epilogue: fp32, out = acc*rsk + bpf; 4 passes of 64 rows through [64][264] f32 tile
    float* ftile = (float*)lds;
#pragma unroll
    for (int p = 0; p < 4; ++p) {
        __syncthreads();
        if (wm == (p >> 1)) {
            float bv[4];
#pragma unroll
            for (int n = 0; n < 4; ++n) bv[n] = bpf[col0 + wn * 64 + n * 16 + l16];
#pragma unroll
            for (int mi = 0; mi < 4; ++mi) {
                int m = (p & 1) * 4 + mi;
                int rowl = mi * 16 + quad * 4;
                int rowb = row0 + p * 64 + rowl;
                float4 k4 = *(const float4*)&ssqK[rowb];
                float rsk4[4];
                rsk4[0] = rsqrtf(fmaxf(k4.x, 1e-12f));
                rsk4[1] = rsqrtf(fmaxf(k4.y, 1e-12f));
                rsk4[2] = rsqrtf(fmaxf(k4.z, 1e-12f));
                rsk4[3] = rsqrtf(fmaxf(k4.w, 1e-12f));
#pragma unroll
                for (int n = 0; n < 4; ++n) {
                    int tcol = wn * 64 + n * 16 + l16;
#pragma unroll
                    for (int t = 0; t < 4; ++t)
                        ftile[(rowl + t) * 264 + tcol] = acc[m][n][t] * rsk4[t] + bv[n];
                }
            }
        }
        __syncthreads();
#pragma unroll
        for (int c = 0; c < 8; ++c) {
            int r  = c * 8 + wave;
            int cu = lane * 4;
            float4 v = *(const float4*)&ftile[r * 264 + cu];
            *(float4*)&C32[(size_t)(row0 + p * 64 + r) * 512 + col0 + cu] = v;
        }
    }
}

// ============ small 128²-tile GEMM (for P^T = (wf^T) @ wp^T-form), bf16 out ============
// C16[m][n] = sum_k A[m][k]*Bt[n][k]; single-buffer R5 body (proven 58.6us at scale).
__global__ __launch_bounds__(256) void gemm128_kernel(
    const u16* __restrict__ A, int lda,
    const u16* __restrict__ Bt, int ldb,
    u16* __restrict__ C16, int ldc, int K)
{
    __shared__ __attribute__((aligned(16))) u16 lds[128 * 132];  // 33792 B
    u16* lsA = lds;
    u16* lsB = lds + 128 * BK;
    const int tid  = threadIdx.x;
    const int wave = tid >> 6;
    const int lane = tid & 63;
    const int quad = lane >> 4;
    const int l16  = lane & 15;
    const int wm = wave >> 1, wn = wave & 1;

    const int gx   = gridDim.x;
    const int nwg  = gx * gridDim.y;            // 16, %8==0
    const int wgid = blockIdx.y * gx + blockIdx.x;
    const int cpx  = nwg >> 3;
    const int swz  = (wgid & 7) * cpx + (wgid >> 3);
    const int row0 = (swz / gx) * 128;
    const int col0 = (swz % gx) * 128;

    floatx4 acc[4][4] = {};
    const int rsub = lane >> 3;
    const int ksub = ((lane & 7) ^ rsub) << 3;
    const u16* aptr[4]; const u16* bptr[4];
#pragma unroll
    for (int c = 0; c < 4; ++c) {
        const int cc = wave * 4 + c;
        aptr[c] = A  + (size_t)(row0 + cc * 8 + rsub) * lda + ksub;
        bptr[c] = Bt + (size_t)(col0 + cc * 8 + rsub) * ldb + ksub;
    }
    for (int kt = 0; kt < K; kt += BK) {
#pragma unroll
        for (int c = 0; c < 4; ++c) {
            const int cc = wave * 4 + c;
            gload_lds16(aptr[c] + kt, &lsA[cc * 512]);
            gload_lds16(bptr[c] + kt, &lsB[cc * 512]);
        }
        __syncthreads();
#pragma unroll
        for (int ks = 0; ks < 2; ++ks) {
            const int pgo = (((ks * 4 + quad) ^ (l16 & 7)) << 3);
            bf16x8 af[4], bfr[4];
#pragma unroll
            for (int i = 0; i < 4; ++i)
                af[i] = *(const bf16x8*)&lsA[(wm * 64 + i * 16 + l16) * BK + pgo];
#pragma unroll
            for (int j = 0; j < 4; ++j)
                bfr[j] = *(const bf16x8*)&lsB[(wn * 64 + j * 16 + l16) * BK + pgo];
#pragma unroll
            for (int i = 0; i < 4; ++i)
#pragma unroll
                for (int j = 0; j < 4; ++j)
                    acc[i][j] = __builtin_amdgcn_mfma_f32_16x16x32_bf16(af[i], bfr[j], acc[i][j], 0, 0, 0);
        }
        __syncthreads();
    }
    // plain bf16 epilogue through [128][132] repack
#pragma unroll
    for (int j = 0; j < 4; ++j) {
        int tcol = wn * 64 + j * 16 + l16;
#pragma unroll
        for (int i = 0; i < 4; ++i) {
            int trow = wm * 64 + i * 16 + quad * 4;
#pragma unroll
            for (int t = 0; t < 4; ++t)
                lds[(trow + t) * 132 + tcol] = f2bf(acc[i][j][t]);
        }
    }
    __syncthreads();
#pragma unroll
    for (int c = 0; c < 8; ++c) {
        int r  = c * 16 + (tid >> 4);
        int cu = (tid & 15) * 8;
        ushort4 lo = *(const ushort4*)&lds[r * 132 + cu];
        ushort4 hi = *(const ushort4*)&lds[r * 132 + cu + 4];
        u16x8 o;
        o[0] = lo.x; o[1] = lo.y; o[2] = lo.z; o[3] = lo.w;
        o[4] = hi.x; o[5] = hi.y; o[6] = hi.z; o[7] = hi.w;
        *(u16x8*)&C16[(size_t)(row0 + r) * ldc + col0 + cu] = o;
    }
}

// g[b,:] += sum_rows rsqrt(ssqQ[row]) * Q[row,:]   (Q = cols 0..511 of QK, raw bf16)
__global__ __launch_bounds__(256) void gsum_kernel(const u16* __restrict__ QK,
                                                   const float* __restrict__ ssqQ,
                                                   float* __restrict__ g)
{
    __shared__ float gtile[4][512];
    const int lane = threadIdx.x & 63;
    const int wave = threadIdx.x >> 6;
    const int row0 = blockIdx.x * 128 + wave * 32;
    const int batch = row0 >> 12;
    const int d = lane * 8;
    float gacc[8] = {};
    for (int rr = 0; rr < 32; ++rr) {
        int row = row0 + rr;
        float s = rsqrtf(fmaxf(ssqQ[row], 1e-12f));
        u16x8 q = *(const u16x8*)(QK + (size_t)row * 1024 + d);
#pragma unroll
        for (int i = 0; i < 8; ++i) gacc[i] += s * bf2f(q[i]);
    }
#pragma unroll
    for (int i = 0; i < 8; ++i) gtile[wave][d + i] = gacc[i];
    __syncthreads();
    int c2 = threadIdx.x * 2;
    float s0 = gtile[0][c2]     + gtile[1][c2]     + gtile[2][c2]     + gtile[3][c2];
    float s1 = gtile[0][c2 + 1] + gtile[1][c2 + 1] + gtile[2][c2 + 1] + gtile[3][c2 + 1];
    atomicAdd(&g[batch * 512 + c2], s0);
    atomicAdd(&g[batch * 512 + c2 + 1], s1);
}

// BtPF[b][n][kk] = g_b[kk] * Pt[n][kk]   (8x512x512, vectorized 8-wide)
__global__ __launch_bounds__(256) void scalePF_kernel(const u16* __restrict__ Pt,
                                                      const float* __restrict__ g,
                                                      u16* __restrict__ BtPF)
{
    size_t i8 = ((size_t)blockIdx.x * 256 + threadIdx.x) * 8;  // over 2,097,152
    int b   = (int)(i8 >> 18);
    int rem = (int)(i8 & 262143);
    int kk  = rem & 511;
    u16x8 p = *(const u16x8*)(Pt + rem);
    float4 g0 = *(const float4*)(g + b * 512 + kk);
    float4 g1 = *(const float4*)(g + b * 512 + kk + 4);
    u16x8 o;
    o[0] = f2bf(bf2f(p[0]) * g0.x); o[1] = f2bf(bf2f(p[1]) * g0.y);
    o[2] = f2bf(bf2f(p[2]) * g0.z); o[3] = f2bf(bf2f(p[3]) * g0.w);
    o[4] = f2bf(bf2f(p[4]) * g1.x); o[5] = f2bf(bf2f(p[5]) * g1.y);
    o[6] = f2bf(bf2f(p[6]) * g1.z); o[7] = f2bf(bf2f(p[7]) * g1.w);
    *(u16x8*)(BtPF + (size_t)b * 262144 + rem) = o;
}

// bpf[n] = sum_j bp[j]*wf[j][n] + bf[n]   (8 blocks x 64-row chunks, atomic combine)
__global__ __launch_bounds__(512) void bpf_kernel(const float* __restrict__ wf,
                                                  const float* __restrict__ bp,
                                                  const float* __restrict__ bfv,
                                                  float* __restrict__ bpf)
{
    int n = threadIdx.x;
    int j0 = blockIdx.x * 64;
    float s = 0.f;
#pragma unroll 8
    for (int j = j0; j < j0 + 64; ++j) s += bp[j] * wf[(size_t)j * 512 + n];
    if (blockIdx.x == 0) s += bfv[n];
    atomicAdd(&bpf[n], s);
}

// x (fp32) -> bf16
__global__ __launch_bounds__(256) void convert_x_kernel(const float* __restrict__ x, u16* __restrict__ xb)
{
    size_t i = ((size_t)blockIdx.x * 256 + threadIdx.x) * 4;
    float4 v = *(const float4*)(x + i);
    ushort4 o;
    o.x = f2bf(v.x); o.y = f2bf(v.y); o.z = f2bf(v.z); o.w = f2bf(v.w);
    *(ushort4*)(xb + i) = o;
}

// wp (fp32) -> bf16 row-major copy (512x512)
__global__ __launch_bounds__(256) void convert_wp_kernel(const float* __restrict__ wp, u16* __restrict__ wpb)
{
    size_t i = ((size_t)blockIdx.x * 256 + threadIdx.x) * 4;
    float4 v = *(const float4*)(wp + i);
    ushort4 o;
    o.x = f2bf(v.x); o.y = f2bf(v.y); o.z = f2bf(v.z); o.w = f2bf(v.w);
    *(ushort4*)(wpb + i) = o;
}

// LDS-tiled transpose of three 512x512 fp32 weights (wq, wk, wf) -> bf16 B^T layout.
__global__ __launch_bounds__(256) void transpose3_kernel(
    const float* __restrict__ w0, const float* __restrict__ w1, const float* __restrict__ w2,
    u16* __restrict__ d0, u16* __restrict__ d1, u16* __restrict__ d2)
{
    __shared__ u16 tile[32][34];
    const int which = blockIdx.x >> 8;
    const float* W = (which == 0) ? w0 : (which == 1) ? w1 : w2;
    u16* Bt = (which == 0) ? d0 : (which == 1) ? d1 : d2;
    const int bid = blockIdx.x & 255;
    const int tk = bid & 15;
    const int tn = bid >> 4;
    const int c  = threadIdx.x & 31;
    const int r0 = threadIdx.x >> 5;
#pragma unroll
    for (int i = 0; i < 4; ++i) {
        int r = r0 + i * 8;
        tile[r][c] = f2bf(W[(size_t)(tk * 32 + r) * 512 + tn * 32 + c]);
    }
    __syncthreads();
#pragma unroll
    for (int i = 0; i < 4; ++i) {
        int r = r0 + i * 8;
        Bt[(size_t)(tn * 32 + r) * 512 + tk * 32 + c] = tile[c][r];
    }
}

// setup: biasQK = [bq|bk]; g = 0; ssq = 0; bpf = 0
__global__ __launch_bounds__(256) void setup_kernel(const float* __restrict__ bq,
                                                    const float* __restrict__ bk,
                                                    float* __restrict__ biasQK,
                                                    float* __restrict__ g,
                                                    float* __restrict__ ssq,
                                                    float* __restrict__ bpf)
{
    int id = blockIdx.x * 256 + threadIdx.x;   // 0..65535
    if (id < 1024) biasQK[id] = (id < 512) ? bq[id] : bk[id - 512];
    if (id < 4096) g[id] = 0.f;
    if (id < 512)  bpf[id] = 0.f;
    ssq[id] = 0.f;                             // 2 x 32768
}

extern "C" void kernel_launch(void* const* d_in, const int* in_sizes, int n_in,
                              void* d_out, int out_size, void* d_ws, size_t ws_size,
                              hipStream_t stream)
{
    const float* x  = (const float*)d_in[0];
    const float* wq = (const float*)d_in[1];
    const float* bq = (const float*)d_in[2];
    const float* wk = (const float*)d_in[3];
    const float* bk = (const float*)d_in[4];
    const float* wp = (const float*)d_in[5];
    const float* bp = (const float*)d_in[6];
    const float* wf = (const float*)d_in[7];
    const float* bf = (const float*)d_in[8];
    // d_in[9] = w_g unused: softmax over a size-1 axis is identically 1.

    char* ws = (char*)d_ws;
    u16*   xb     = (u16*)(ws);                 // 32768x512 bf16 = 32 MiB
    u16*   QK     = (u16*)(ws + 33554432);      // 32768x1024 bf16 = 64 MiB
    u16*   Bt1    = (u16*)(ws + 100663296);     // 1024x512
    u16*   BtF    = (u16*)(ws + 101711872);     // 512x512 (wf^T)
    u16*   wpb    = (u16*)(ws + 102236160);     // 512x512 (wp bf16, row-major)
    u16*   Pt     = (u16*)(ws + 102760448);     // 512x512 ((wp@wf)^T, n-major)
    u16*   BtPF   = (u16*)(ws + 103284736);     // 8x512x512 = 4 MiB
    float* biasQK = (float*)(ws + 107479040);   // 1024
    float* g      = (float*)(ws + 107483136);   // 8x512
    float* ssq    = (float*)(ws + 107499520);   // 2x32768 (Q, K)
    float* bpf    = (float*)(ws + 107761664);   // 512

    setup_kernel<<<256, 256, 0, stream>>>(bq, bk, biasQK, g, ssq, bpf);
    convert_x_kernel<<<16384, 256, 0, stream>>>(x, xb);
    transpose3_kernel<<<768, 256, 0, stream>>>(wq, wk, wf, Bt1, Bt1 + 512 * 512, BtF);
    convert_wp_kernel<<<256, 256, 0, stream>>>(wp, wpb);
    bpf_kernel<<<8, 512, 0, stream>>>(wf, bp, bf, bpf);
    // Pt[n][kk] = sum_j wf[j][n]*wp[kk][j] = (wp@wf)^T  (g-independent, runs early)
    gemm128_kernel<<<dim3(4, 4), 256, 0, stream>>>(BtF, 512, wpb, 512, Pt, 512, 512);

    // QK = x @ [wq|wk] + [bq|bk]  (bf16) + per-row ssq of Q,K halves        nwg = 512
    gemm1_kernel<<<dim3(4, 128), 512, 0, stream>>>(xb, Bt1, biasQK, ssq, QK);
    // g[b,:] = sum_rows rsqrt(ssqQ[r]) * Q[r,:]
    gsum_kernel<<<256, 256, 0, stream>>>(QK, ssq, g);
    // BtPF[b] = diag-scale of Pt by g_b
    scalePF_kernel<<<1024, 256, 0, stream>>>(Pt, g, BtPF);
    // out = rsq*(Q@wf) + rsk*(K@diag(g)(wp@wf)) + bp@wf + bf   (fp32)       nwg = 256
    gemm_qk_kernel<<<dim3(2, 128), 512, 0, stream>>>(QK, BtF, BtPF, bpf, ssq, ssq + 32768, (float*)d_out);
}

// Round 9
// 244.336 us; speedup vs baseline: 1.0532x; 1.0479x over previous
//
#include <hip/hip_runtime.h>
#include <stdint.h>

typedef __bf16 bf16x8 __attribute__((ext_vector_type(8)));
typedef float floatx4 __attribute__((ext_vector_type(4)));
typedef unsigned short u16;
typedef u16 u16x8 __attribute__((ext_vector_type(8)));

__device__ __forceinline__ float bf2f(u16 u) {
    union { uint32_t i; float f; } v; v.i = ((uint32_t)u) << 16; return v.f;
}
__device__ __forceinline__ u16 f2bf(float f) {
    union { float f; uint32_t i; } v; v.f = f;
    uint32_t r = v.i + 0x7fffu + ((v.i >> 16) & 1u);
    return (u16)(r >> 16);
}

// async global->LDS, 16B per lane. LDS dest wave-uniform base; HW adds lane*16.
__device__ __forceinline__ void gload_lds16(const u16* g, u16* l) {
    __builtin_amdgcn_global_load_lds(
        (const __attribute__((address_space(1))) void*)g,
        (__attribute__((address_space(3))) void*)l,
        16, 0, 0);
}

#define BK 64

// ============ GEMM1: QK = xb @ [wq|wk]^T + biasQK, bf16 out + per-row ssq =============
// 256x256 tile, 8 waves, depth-2 counted-vmcnt body (proven R6-R8). lda=512, ldc=1024, K=512.
__global__ __launch_bounds__(512, 2) void gemm1_kernel(
    const u16* __restrict__ A,        // xb [32768][512]
    const u16* __restrict__ Bt,       // Bt1 [1024][512]
    const float* __restrict__ bias,   // biasQK [1024]
    float* __restrict__ ssq_out,      // [2][32768]
    u16* __restrict__ C16)            // QK [32768][1024]
{
    __shared__ __attribute__((aligned(16))) u16 lds[2 * 32768];  // 128 KiB
    const int tid  = threadIdx.x;
    const int wave = tid >> 6;
    const int lane = tid & 63;
    const int quad = lane >> 4;
    const int l16  = lane & 15;
    const int wm = wave >> 2, wn = wave & 3;

    const int gx   = gridDim.x;                 // 4
    const int nwg  = gx * gridDim.y;            // 512, %8==0
    const int wgid = blockIdx.y * gx + blockIdx.x;
    const int cpx  = nwg >> 3;
    const int swz  = (wgid & 7) * cpx + (wgid >> 3);
    const int row0 = (swz / gx) * 256;
    const int col0 = (swz % gx) * 256;

    floatx4 acc[8][4] = {};

    const int rsub = lane >> 3;
    const int ksub = ((lane & 7) ^ rsub) << 3;  // XOR pre-swizzle (rule 21)
    const u16* aptr[4]; const u16* bptr[4];
#pragma unroll
    for (int c = 0; c < 4; ++c) {
        const int cc = wave * 4 + c;
        aptr[c] = A  + (size_t)(row0 + cc * 8 + rsub) * 512 + ksub;
        bptr[c] = Bt + (size_t)(col0 + cc * 8 + rsub) * 512 + ksub;
    }
    const int NT = 8;

#define STAGE1(T, B)                                                          \
    {                                                                         \
        u16* dA_ = &lds[(B) * 32768];                                         \
        u16* dB_ = dA_ + 16384;                                               \
        const int kt_ = (T) * BK;                                             \
        _Pragma("unroll")                                                     \
        for (int c = 0; c < 4; ++c) {                                         \
            const int cc = wave * 4 + c;                                      \
            gload_lds16(aptr[c] + kt_, dA_ + cc * 512);                       \
            gload_lds16(bptr[c] + kt_, dB_ + cc * 512);                       \
        }                                                                     \
    }

    STAGE1(0, 0);
    STAGE1(1, 1);
    for (int t = 0; t < NT; ++t) {
        if (t + 1 < NT) asm volatile("s_waitcnt vmcnt(8)" ::: "memory");
        else            asm volatile("s_waitcnt vmcnt(0)" ::: "memory");
        __builtin_amdgcn_s_barrier();
        __builtin_amdgcn_sched_barrier(0);
        const u16* sA = &lds[(t & 1) * 32768];
        const u16* sB = sA + 16384;
#pragma unroll
        for (int ks = 0; ks < 2; ++ks) {
            const int pgo = (((ks * 4 + quad) ^ (l16 & 7)) << 3);
            bf16x8 bfr[4];
#pragma unroll
            for (int n = 0; n < 4; ++n)
                bfr[n] = *(const bf16x8*)&sB[(wn * 64 + n * 16 + l16) * 64 + pgo];
            __builtin_amdgcn_s_setprio(1);
#pragma unroll
            for (int m = 0; m < 8; ++m) {
                bf16x8 af = *(const bf16x8*)&sA[(wm * 128 + m * 16 + l16) * 64 + pgo];
#pragma unroll
                for (int n = 0; n < 4; ++n)
                    acc[m][n] = __builtin_amdgcn_mfma_f32_16x16x32_bf16(af, bfr[n], acc[m][n], 0, 0, 0);
            }
            __builtin_amdgcn_s_setprio(0);
        }
        __builtin_amdgcn_sched_barrier(0);
        asm volatile("" ::: "memory");
        __builtin_amdgcn_s_barrier();
        asm volatile("" ::: "memory");
        if (t + 2 < NT) STAGE1(t + 2, t & 1);
    }
#undef STAGE1

    // epilogue: bf16 repack + per-row output ssq (validated R5-R8)
    u16* til = lds;  // [128][264]
#pragma unroll
    for (int h = 0; h < 2; ++h) {
        __syncthreads();
        if (wm == h) {
            float bv[4];
#pragma unroll
            for (int n = 0; n < 4; ++n) bv[n] = bias[col0 + wn * 64 + n * 16 + l16];
#pragma unroll
            for (int m = 0; m < 8; ++m) {
                int rowl = m * 16 + quad * 4;
#pragma unroll
                for (int n = 0; n < 4; ++n) {
                    int tcol = wn * 64 + n * 16 + l16;
#pragma unroll
                    for (int t = 0; t < 4; ++t)
                        til[(rowl + t) * 264 + tcol] = f2bf(acc[m][n][t] + bv[n]);
                }
            }
        }
        __syncthreads();
        float ssl[8];
#pragma unroll
        for (int c = 0; c < 8; ++c) {
            int r  = c * 16 + (tid >> 5);
            int cu = (tid & 31) * 8;
            ushort4 lo = *(const ushort4*)&til[r * 264 + cu];
            ushort4 hi = *(const ushort4*)&til[r * 264 + cu + 4];
            u16x8 o;
            o[0] = lo.x; o[1] = lo.y; o[2] = lo.z; o[3] = lo.w;
            o[4] = hi.x; o[5] = hi.y; o[6] = hi.z; o[7] = hi.w;
            *(u16x8*)&C16[(size_t)(row0 + h * 128 + r) * 1024 + col0 + cu] = o;
            float ss = 0.f;
#pragma unroll
            for (int q2 = 0; q2 < 8; ++q2) { float f = bf2f(o[q2]); ss += f * f; }
            ssl[c] = ss;
        }
        float* so = ssq_out + (size_t)(col0 >> 9) * 32768 + row0 + h * 128;
#pragma unroll
        for (int c = 0; c < 8; ++c) {
            float s = ssl[c];
            s += __shfl_xor(s, 1);
            s += __shfl_xor(s, 2);
            s += __shfl_xor(s, 4);
            s += __shfl_xor(s, 8);
            s += __shfl_xor(s, 16);
            if ((lane & 31) == 0) atomicAdd(&so[c * 16 + (tid >> 5)], s);
        }
    }
}

// ====== fused GEMM23: out = rsq*(Q@wf) + rsk*(K@diag(g)(wp@wf)) + bpf, fp32 out =======
// Byte-identical body to R8 (proven).
__global__ __launch_bounds__(512, 2) void gemm_qk_kernel(
    const u16* __restrict__ A,        // QK [32768][1024]
    const u16* __restrict__ BtF,      // [512][512] wf^T
    const u16* __restrict__ BtPF,     // [8][512][512] diag(g_b)*(wp@wf), n-major
    const float* __restrict__ bpf,    // [512] = bp@wf + bf
    const float* __restrict__ ssqQ,
    const float* __restrict__ ssqK,
    float* __restrict__ C32)          // out [32768][512]
{
    __shared__ __attribute__((aligned(16))) u16 lds[2 * 32768];  // 128 KiB
    const int tid  = threadIdx.x;
    const int wave = tid >> 6;
    const int lane = tid & 63;
    const int quad = lane >> 4;
    const int l16  = lane & 15;
    const int wm = wave >> 2, wn = wave & 3;

    const int gx   = gridDim.x;                 // 2
    const int nwg  = gx * gridDim.y;            // 256, %8==0
    const int wgid = blockIdx.y * gx + blockIdx.x;
    const int cpx  = nwg >> 3;
    const int swz  = (wgid & 7) * cpx + (wgid >> 3);
    const int row0 = (swz / gx) * 256;
    const int col0 = (swz % gx) * 256;
    const int batch = row0 >> 12;

    floatx4 acc[8][4] = {};

    const int rsub = lane >> 3;
    const int ksub = ((lane & 7) ^ rsub) << 3;
    const u16* aptr[4]; const u16* bptrF[4]; const u16* bptrP[4];
    const u16* BP = BtPF + (size_t)batch * 262144;
#pragma unroll
    for (int c = 0; c < 4; ++c) {
        const int cc = wave * 4 + c;
        aptr[c]  = A   + (size_t)(row0 + cc * 8 + rsub) * 1024 + ksub;
        bptrF[c] = BtF + (size_t)(col0 + cc * 8 + rsub) * 512  + ksub;
        bptrP[c] = BP  + (size_t)(col0 + cc * 8 + rsub) * 512  + ksub;
    }
    const int NT = 16;

#define STAGEQ(T, B)                                                          \
    {                                                                         \
        u16* dA_ = &lds[(B) * 32768];                                         \
        u16* dB_ = dA_ + 16384;                                               \
        const int kt_ = (T) * BK;                                             \
        _Pragma("unroll")                                                     \
        for (int c = 0; c < 4; ++c) {                                         \
            const int cc = wave * 4 + c;                                      \
            gload_lds16(aptr[c] + kt_, dA_ + cc * 512);                       \
            const u16* bsrc_ = (kt_ < 512) ? (bptrF[c] + kt_)                 \
                                           : (bptrP[c] + (kt_ - 512));        \
            gload_lds16(bsrc_, dB_ + cc * 512);                               \
        }                                                                     \
    }

    STAGEQ(0, 0);
    STAGEQ(1, 1);
    for (int t = 0; t < NT; ++t) {
        if (t + 1 < NT) asm volatile("s_waitcnt vmcnt(8)" ::: "memory");
        else            asm volatile("s_waitcnt vmcnt(0)" ::: "memory");
        __builtin_amdgcn_s_barrier();
        __builtin_amdgcn_sched_barrier(0);
        const u16* sA = &lds[(t & 1) * 32768];
        const u16* sB = sA + 16384;
#pragma unroll
        for (int ks = 0; ks < 2; ++ks) {
            const int pgo = (((ks * 4 + quad) ^ (l16 & 7)) << 3);
            bf16x8 bfr[4];
#pragma unroll
            for (int n = 0; n < 4; ++n)
                bfr[n] = *(const bf16x8*)&sB[(wn * 64 + n * 16 + l16) * 64 + pgo];
            __builtin_amdgcn_s_setprio(1);
#pragma unroll
            for (int m = 0; m < 8; ++m) {
                bf16x8 af = *(const bf16x8*)&sA[(wm * 128 + m * 16 + l16) * 64 + pgo];
#pragma unroll
                for (int n = 0; n < 4; ++n)
                    acc[m][n] = __builtin_amdgcn_mfma_f32_16x16x32_bf16(af, bfr[n], acc[m][n], 0, 0, 0);
            }
            __builtin_amdgcn_s_setprio(0);
        }
        // end of Q-half: acc holds Sq = Q@wf; rescale so final *rsk yields rsq*Sq + rsk*Sk
        if (t == 7) {
#pragma unroll
            for (int m = 0; m < 8; ++m) {
                int rowb = row0 + wm * 128 + m * 16 + quad * 4;
                float4 q4 = *(const float4*)&ssqQ[rowb];
                float4 k4 = *(const float4*)&ssqK[rowb];
                float ratio[4];
                ratio[0] = rsqrtf(fmaxf(q4.x, 1e-12f)) / rsqrtf(fmaxf(k4.x, 1e-12f));
                ratio[1] = rsqrtf(fmaxf(q4.y, 1e-12f)) / rsqrtf(fmaxf(k4.y, 1e-12f));
                ratio[2] = rsqrtf(fmaxf(q4.z, 1e-12f)) / rsqrtf(fmaxf(k4.z, 1e-12f));
                ratio[3] = rsqrtf(fmaxf(q4.w, 1e-12f)) / rsqrtf(fmaxf(k4.w, 1e-12f));
#pragma unroll
                for (int n = 0; n < 4; ++n)
#pragma unroll
                    for (int tt = 0; tt < 4; ++tt)
                        acc[m][n][tt] *= ratio[tt];
            }
        }
        __builtin_amdgcn_sched_barrier(0);
        asm volatile("" ::: "memory");
        __builtin_amdgcn_s_barrier();
        asm volatile("" ::: "memory");
        if (t + 2 < NT) STAGEQ(t + 2, t & 1);
    }
#undef STAGEQ

    // epilogue: fp32, out = acc*rsk + bpf; 4 passes of 64 rows through [64][264] f32 tile
    float* ftile = (float*)lds;
#pragma unroll
    for (int p = 0; p < 4; ++p) {
        __syncthreads();
        if (wm == (p >> 1)) {
            float bv[4];
#pragma unroll
            for (int n = 0; n < 4; ++n) bv[n] = bpf[col0 + wn * 64 + n * 16 + l16];
#pragma unroll
            for (int mi = 0; mi < 4; ++mi) {
                int m = (p & 1) * 4 + mi;
                int rowl = mi * 16 + quad * 4;
                int rowb = row0 + p * 64 + rowl;
                float4 k4 = *(const float4*)&ssqK[rowb];
                float rsk4[4];
                rsk4[0] = rsqrtf(fmaxf(k4.x, 1e-12f));
                rsk4[1] = rsqrtf(fmaxf(k4.y, 1e-12f));
                rsk4[2] = rsqrtf(fmaxf(k4.z, 1e-12f));
                rsk4[3] = rsqrtf(fmaxf(k4.w, 1e-12f));
#pragma unroll
                for (int n = 0; n < 4; ++n) {
                    int tcol = wn * 64 + n * 16 + l16;
#pragma unroll
                    for (int t = 0; t < 4; ++t)
                        ftile[(rowl + t) * 264 + tcol] = acc[m][n][t] * rsk4[t] + bv[n];
                }
            }
        }
        __syncthreads();
#pragma unroll
        for (int c = 0; c < 8; ++c) {
            int r  = c * 8 + wave;
            int cu = lane * 4;
            float4 v = *(const float4*)&ftile[r * 264 + cu];
            *(float4*)&C32[(size_t)(row0 + p * 64 + r) * 512 + col0 + cu] = v;
        }
    }
}

// ====== gsum_p: blocks [0,256) gsum; blocks [256,272) P^T GEMM (independent work) ======
// gsum: g[b,:] += sum_rows rsqrt(ssqQ[row]) * Q[row,:]
// P:    Pt[n][kk] = (wp@wf)^T via 128x128-tile MFMA GEMM (A=BtF, B=wpb, K=512)
__global__ __launch_bounds__(256) void gsum_p_kernel(
    const u16* __restrict__ QK, const float* __restrict__ ssqQ, float* __restrict__ g,
    const u16* __restrict__ BtF, const u16* __restrict__ wpb, u16* __restrict__ Pt)
{
    __shared__ __attribute__((aligned(16))) char shmem[128 * 132 * 2];  // 33792 B
    const int tid  = threadIdx.x;
    const int lane = tid & 63;
    const int wave = tid >> 6;

    if (blockIdx.x < 256) {
        // ---- gsum role (body unchanged from R5-R8) ----
        float (*gtile)[512] = (float(*)[512])shmem;
        const int row0 = blockIdx.x * 128 + wave * 32;
        const int batch = row0 >> 12;
        const int d = lane * 8;
        float gacc[8] = {};
        for (int rr = 0; rr < 32; ++rr) {
            int row = row0 + rr;
            float s = rsqrtf(fmaxf(ssqQ[row], 1e-12f));
            u16x8 q = *(const u16x8*)(QK + (size_t)row * 1024 + d);
#pragma unroll
            for (int i = 0; i < 8; ++i) gacc[i] += s * bf2f(q[i]);
        }
#pragma unroll
        for (int i = 0; i < 8; ++i) gtile[wave][d + i] = gacc[i];
        __syncthreads();
        int c2 = tid * 2;
        float s0 = gtile[0][c2]     + gtile[1][c2]     + gtile[2][c2]     + gtile[3][c2];
        float s1 = gtile[0][c2 + 1] + gtile[1][c2 + 1] + gtile[2][c2 + 1] + gtile[3][c2 + 1];
        atomicAdd(&g[batch * 512 + c2], s0);
        atomicAdd(&g[batch * 512 + c2 + 1], s1);
        return;
    }

    // ---- P role: 16 blocks, 128x128 tiles of Pt = (wp@wf)^T ----
    u16* lds  = (u16*)shmem;
    u16* lsA  = lds;
    u16* lsB  = lds + 128 * BK;
    const int quad = lane >> 4;
    const int l16  = lane & 15;
    const int wm = wave >> 1, wn = wave & 1;
    const int bid2 = blockIdx.x - 256;
    const int row0 = (bid2 >> 2) * 128;
    const int col0 = (bid2 & 3) * 128;

    floatx4 acc[4][4] = {};
    const int rsub = lane >> 3;
    const int ksub = ((lane & 7) ^ rsub) << 3;
    const u16* aptr[4]; const u16* bptr[4];
#pragma unroll
    for (int c = 0; c < 4; ++c) {
        const int cc = wave * 4 + c;
        aptr[c] = BtF + (size_t)(row0 + cc * 8 + rsub) * 512 + ksub;
        bptr[c] = wpb + (size_t)(col0 + cc * 8 + rsub) * 512 + ksub;
    }
    for (int kt = 0; kt < 512; kt += BK) {
#pragma unroll
        for (int c = 0; c < 4; ++c) {
            const int cc = wave * 4 + c;
            gload_lds16(aptr[c] + kt, &lsA[cc * 512]);
            gload_lds16(bptr[c] + kt, &lsB[cc * 512]);
        }
        __syncthreads();
#pragma unroll
        for (int ks = 0; ks < 2; ++ks) {
            const int pgo = (((ks * 4 + quad) ^ (l16 & 7)) << 3);
            bf16x8 af[4], bfr[4];
#pragma unroll
            for (int i = 0; i < 4; ++i)
                af[i] = *(const bf16x8*)&lsA[(wm * 64 + i * 16 + l16) * BK + pgo];
#pragma unroll
            for (int j = 0; j < 4; ++j)
                bfr[j] = *(const bf16x8*)&lsB[(wn * 64 + j * 16 + l16) * BK + pgo];
#pragma unroll
            for (int i = 0; i < 4; ++i)
#pragma unroll
                for (int j = 0; j < 4; ++j)
                    acc[i][j] = __builtin_amdgcn_mfma_f32_16x16x32_bf16(af[i], bfr[j], acc[i][j], 0, 0, 0);
        }
        __syncthreads();
    }
#pragma unroll
    for (int j = 0; j < 4; ++j) {
        int tcol = wn * 64 + j * 16 + l16;
#pragma unroll
        for (int i = 0; i < 4; ++i) {
            int trow = wm * 64 + i * 16 + quad * 4;
#pragma unroll
            for (int t = 0; t < 4; ++t)
                lds[(trow + t) * 132 + tcol] = f2bf(acc[i][j][t]);
        }
    }
    __syncthreads();
#pragma unroll
    for (int c = 0; c < 8; ++c) {
        int r  = c * 16 + (tid >> 4);
        int cu = (tid & 15) * 8;
        ushort4 lo = *(const ushort4*)&lds[r * 132 + cu];
        ushort4 hi = *(const ushort4*)&lds[r * 132 + cu + 4];
        u16x8 o;
        o[0] = lo.x; o[1] = lo.y; o[2] = lo.z; o[3] = lo.w;
        o[4] = hi.x; o[5] = hi.y; o[6] = hi.z; o[7] = hi.w;
        *(u16x8*)&Pt[(size_t)(row0 + r) * 512 + col0 + cu] = o;
    }
}

// BtPF[b][n][kk] = g_b[kk] * Pt[n][kk]   (8x512x512, vectorized 8-wide)
__global__ __launch_bounds__(256) void scalePF_kernel(const u16* __restrict__ Pt,
                                                      const float* __restrict__ g,
                                                      u16* __restrict__ BtPF)
{
    size_t i8 = ((size_t)blockIdx.x * 256 + threadIdx.x) * 8;  // over 2,097,152
    int b   = (int)(i8 >> 18);
    int rem = (int)(i8 & 262143);
    int kk  = rem & 511;
    u16x8 p = *(const u16x8*)(Pt + rem);
    float4 g0 = *(const float4*)(g + b * 512 + kk);
    float4 g1 = *(const float4*)(g + b * 512 + kk + 4);
    u16x8 o;
    o[0] = f2bf(bf2f(p[0]) * g0.x); o[1] = f2bf(bf2f(p[1]) * g0.y);
    o[2] = f2bf(bf2f(p[2]) * g0.z); o[3] = f2bf(bf2f(p[3]) * g0.w);
    o[4] = f2bf(bf2f(p[4]) * g1.x); o[5] = f2bf(bf2f(p[5]) * g1.y);
    o[6] = f2bf(bf2f(p[6]) * g1.z); o[7] = f2bf(bf2f(p[7]) * g1.w);
    *(u16x8*)(BtPF + (size_t)b * 262144 + rem) = o;
}

// ====== prep: one launch for convert_x + transpose3 + convert_wp + biasQK + bpf ======
// role by blockIdx range: [0,16384) convert_x; [16384,17152) transpose3;
// [17152,17408) convert_wp; [17408,17412) biasQK; [17412,17428) bpf.
// bpf is zero-initialized by the preceding hipMemsetAsync (no intra-launch race).
__global__ __launch_bounds__(256) void prep_kernel(
    const float* __restrict__ x,  u16* __restrict__ xb,
    const float* __restrict__ wq, const float* __restrict__ wk, const float* __restrict__ wf,
    u16* __restrict__ Bt1, u16* __restrict__ BtF,
    const float* __restrict__ wp, u16* __restrict__ wpb,
    const float* __restrict__ bq, const float* __restrict__ bk, float* __restrict__ biasQK,
    const float* __restrict__ bp, const float* __restrict__ bfv, float* __restrict__ bpf)
{
    __shared__ u16 tile[32][34];
    const int bid = blockIdx.x;
    const int tid = threadIdx.x;

    if (bid < 16384) {                       // convert_x: fp32 -> bf16, 16.7M elems
        size_t i = ((size_t)bid * 256 + tid) * 4;
        float4 v = *(const float4*)(x + i);
        ushort4 o;
        o.x = f2bf(v.x); o.y = f2bf(v.y); o.z = f2bf(v.z); o.w = f2bf(v.w);
        *(ushort4*)(xb + i) = o;
    } else if (bid < 17152) {                // transpose3: wq,wk,wf -> B^T bf16
        const int tb = bid - 16384;
        const int which = tb >> 8;
        const float* W = (which == 0) ? wq : (which == 1) ? wk : wf;
        u16* Bt = (which == 0) ? Bt1 : (which == 1) ? (Bt1 + 512 * 512) : BtF;
        const int b2 = tb & 255;
        const int tk = b2 & 15;
        const int tn = b2 >> 4;
        const int c  = tid & 31;
        const int r0 = tid >> 5;
#pragma unroll
        for (int i = 0; i < 4; ++i) {
            int r = r0 + i * 8;
            tile[r][c] = f2bf(W[(size_t)(tk * 32 + r) * 512 + tn * 32 + c]);
        }
        __syncthreads();
#pragma unroll
        for (int i = 0; i < 4; ++i) {
            int r = r0 + i * 8;
            Bt[(size_t)(tn * 32 + r) * 512 + tk * 32 + c] = tile[c][r];
        }
    } else if (bid < 17408) {                // convert_wp: fp32 -> bf16 row-major
        size_t i = ((size_t)(bid - 17152) * 256 + tid) * 4;
        float4 v = *(const float4*)(wp + i);
        ushort4 o;
        o.x = f2bf(v.x); o.y = f2bf(v.y); o.z = f2bf(v.z); o.w = f2bf(v.w);
        *(ushort4*)(wpb + i) = o;
    } else if (bid < 17412) {                // biasQK = [bq|bk]
        int id = (bid - 17408) * 256 + tid;  // 0..1023
        biasQK[id] = (id < 512) ? bq[id] : bk[id - 512];
    } else {                                 // bpf += partial(bp@wf) [+ bf]
        const int bb = bid - 17412;          // 0..15
        const int j0 = bb * 32;
        float s0 = 0.f, s1 = 0.f;
#pragma unroll 4
        for (int j = j0; j < j0 + 32; ++j) {
            s0 += bp[j] * wf[(size_t)j * 512 + tid];
            s1 += bp[j] * wf[(size_t)j * 512 + tid + 256];
        }
        if (bb == 0) { s0 += bfv[tid]; s1 += bfv[tid + 256]; }
        atomicAdd(&bpf[tid], s0);
        atomicAdd(&bpf[tid + 256], s1);
    }
}

extern "C" void kernel_launch(void* const* d_in, const int* in_sizes, int n_in,
                              void* d_out, int out_size, void* d_ws, size_t ws_size,
                              hipStream_t stream)
{
    const float* x  = (const float*)d_in[0];
    const float* wq = (const float*)d_in[1];
    const float* bq = (const float*)d_in[2];
    const float* wk = (const float*)d_in[3];
    const float* bk = (const float*)d_in[4];
    const float* wp = (const float*)d_in[5];
    const float* bp = (const float*)d_in[6];
    const float* wf = (const float*)d_in[7];
    const float* bf = (const float*)d_in[8];
    // d_in[9] = w_g unused: softmax over a size-1 axis is identically 1.

    char* ws = (char*)d_ws;
    u16*   xb     = (u16*)(ws);                 // 32768x512 bf16 = 32 MiB
    u16*   QK     = (u16*)(ws + 33554432);      // 32768x1024 bf16 = 64 MiB
    u16*   Bt1    = (u16*)(ws + 100663296);     // 1024x512
    u16*   BtF    = (u16*)(ws + 101711872);     // 512x512 (wf^T)
    u16*   wpb    = (u16*)(ws + 102236160);     // 512x512 (wp bf16, row-major)
    u16*   Pt     = (u16*)(ws + 102760448);     // 512x512 ((wp@wf)^T, n-major)
    u16*   BtPF   = (u16*)(ws + 103284736);     // 8x512x512 = 4 MiB
    float* biasQK = (float*)(ws + 107479040);   // 1024
    float* g      = (float*)(ws + 107483136);   // 8x512        (16 KiB)
    float* ssq    = (float*)(ws + 107499520);   // 2x32768      (256 KiB, contiguous after g)
    float* bpf    = (float*)(ws + 107761664);   // 512          (contiguous after ssq)

    // one memset covers g | ssq | bpf (contiguous): 16384 + 262144 + 2048 B
    hipMemsetAsync(g, 0, 280576, stream);
    // prep: convert_x + transpose3 + convert_wp + biasQK + bpf  (one launch)
    prep_kernel<<<17428, 256, 0, stream>>>(x, xb, wq, wk, wf, Bt1, BtF, wp, wpb,
                                           bq, bk, biasQK, bp, bf, bpf);
    // QK = x @ [wq|wk] + [bq|bk]  (bf16) + per-row ssq of Q,K halves        nwg = 512
    gemm1_kernel<<<dim3(4, 128), 512, 0, stream>>>(xb, Bt1, biasQK, ssq, QK);
    // gsum (g) + Pt = (wp@wf)^T  (independent P rides along)                272 blocks
    gsum_p_kernel<<<272, 256, 0, stream>>>(QK, ssq, g, BtF, wpb, Pt);
    // BtPF[b] = diag-scale of Pt by g_b
    scalePF_kernel<<<1024, 256, 0, stream>>>(Pt, g, BtPF);
    // out = rsq*(Q@wf) + rsk*(K@diag(g)(wp@wf)) + bp@wf + bf   (fp32)       nwg = 256
    gemm_qk_kernel<<<dim3(2, 128), 512, 0, stream>>>(QK, BtF, BtPF, bpf, ssq, ssq + 32768, (float*)d_out);
}